// Round 1
// baseline (729.734 us; speedup 1.0000x reference)
//
#include <hip/hip_runtime.h>

// ObjectMeanDirectAttention: per-node attention MLP -> weighted segment mean -> final MLP
// Round 0: all-f32 correctness-first baseline, register-tiled LDS GEMMs.

#define NGRAPHS 4096
#define FXDIM 64
#define TILE_N 64
constexpr int LDP = 68;    // padded LDS stride for 64-wide tiles (16B-aligned rows, bank-spread)
constexpr int LDU = 132;   // padded LDS stride for 128-wide u tile

__device__ __forceinline__ int lower_bound_i(const int* __restrict__ arr, int n, int v) {
    int lo = 0, hi = n;
    while (lo < hi) {
        int mid = (lo + hi) >> 1;
        if (arr[mid] < v) lo = mid + 1; else hi = mid;
    }
    return lo;
}

// C[n0..n0+3][j0..j0+3] += A[n][k] * B[k][j], A stride LDAa, B stride LDBb, K inner
template<int K, int LDAa, int LDBb>
__device__ __forceinline__ void tile_gemm(const float* __restrict__ As,
                                          const float* __restrict__ Bs,
                                          float acc[4][4], int n0, int j0) {
#pragma unroll 4
    for (int k0 = 0; k0 < K; k0 += 4) {
        float4 a[4], w[4];
#pragma unroll
        for (int i = 0; i < 4; i++) a[i] = *(const float4*)&As[(n0 + i) * LDAa + k0];
#pragma unroll
        for (int kk = 0; kk < 4; kk++) w[kk] = *(const float4*)&Bs[(k0 + kk) * LDBb + j0];
#pragma unroll
        for (int i = 0; i < 4; i++) {
            const float av0 = a[i].x, av1 = a[i].y, av2 = a[i].z, av3 = a[i].w;
            acc[i][0] += av0 * w[0].x; acc[i][1] += av0 * w[0].y; acc[i][2] += av0 * w[0].z; acc[i][3] += av0 * w[0].w;
            acc[i][0] += av1 * w[1].x; acc[i][1] += av1 * w[1].y; acc[i][2] += av1 * w[1].z; acc[i][3] += av1 * w[1].w;
            acc[i][0] += av2 * w[2].x; acc[i][1] += av2 * w[2].y; acc[i][2] += av2 * w[2].z; acc[i][3] += av2 * w[2].w;
            acc[i][0] += av3 * w[3].x; acc[i][1] += av3 * w[3].y; acc[i][2] += av3 * w[3].z; acc[i][3] += av3 * w[3].w;
        }
    }
}

// Per-node 3-layer MLP (64->64->64->1) + attention-weighted scatter-add into num[g][col_off + j]
__global__ __launch_bounds__(256)
void attn_scatter_kernel(const float* __restrict__ x, const int* __restrict__ batch, int N,
                         const float* __restrict__ W1, const float* __restrict__ b1,
                         const float* __restrict__ W2, const float* __restrict__ b2,
                         const float* __restrict__ W3, const float* __restrict__ b3,
                         float* __restrict__ num, int col_off) {
    __shared__ float W1s[64 * LDP];
    __shared__ float W2s[64 * LDP];
    __shared__ float As[64 * LDP];   // x tile, later h2
    __shared__ float Hs[64 * LDP];   // h1
    __shared__ float W3s[64];
    __shared__ float a_s[64];
    __shared__ float ps[256];
    __shared__ int   bs[64];

    const int t = threadIdx.x;
    const int base = blockIdx.x * TILE_N;
    const int nvalid = min(TILE_N, N - base);

    // stage weights (64x64 each) as float4
    {
        const float4* W1v = (const float4*)W1;
        const float4* W2v = (const float4*)W2;
#pragma unroll
        for (int r = 0; r < 4; r++) {
            int e4 = t + 256 * r;          // 0..1023
            int e = e4 * 4;
            int k = e / 64, j = e % 64;
            *(float4*)&W1s[k * LDP + j] = W1v[e4];
            *(float4*)&W2s[k * LDP + j] = W2v[e4];
        }
        if (t < 64) {
            W3s[t] = W3[t];
            bs[t] = (base + t < N) ? batch[base + t] : 0;
        }
    }
    // stage x tile (zero-pad tail rows)
    {
#pragma unroll
        for (int r = 0; r < 4; r++) {
            int e4 = t + 256 * r;
            int e = e4 * 4;
            int n = e / 64, j = e % 64;
            float4 v = make_float4(0.f, 0.f, 0.f, 0.f);
            if (base + n < N) v = *(const float4*)&x[(size_t)(base + n) * 64 + j];
            *(float4*)&As[n * LDP + j] = v;
        }
    }
    __syncthreads();

    const int fg = t & 15, ng = t >> 4;
    const int j0 = fg * 4, n0 = ng * 4;

    // layer 1: h1 = relu(x @ W1 + b1)
    float acc[4][4];
#pragma unroll
    for (int i = 0; i < 4; i++) { acc[i][0] = 0.f; acc[i][1] = 0.f; acc[i][2] = 0.f; acc[i][3] = 0.f; }
    tile_gemm<64, LDP, LDP>(As, W1s, acc, n0, j0);
    {
        float4 bb = *(const float4*)&b1[j0];
#pragma unroll
        for (int i = 0; i < 4; i++) {
            float4 hv;
            hv.x = fmaxf(acc[i][0] + bb.x, 0.f);
            hv.y = fmaxf(acc[i][1] + bb.y, 0.f);
            hv.z = fmaxf(acc[i][2] + bb.z, 0.f);
            hv.w = fmaxf(acc[i][3] + bb.w, 0.f);
            *(float4*)&Hs[(n0 + i) * LDP + j0] = hv;
        }
    }
    __syncthreads();

    // layer 2: h2 = relu(h1 @ W2 + b2) -> overwrite As
#pragma unroll
    for (int i = 0; i < 4; i++) { acc[i][0] = 0.f; acc[i][1] = 0.f; acc[i][2] = 0.f; acc[i][3] = 0.f; }
    tile_gemm<64, LDP, LDP>(Hs, W2s, acc, n0, j0);
    {
        float4 bb = *(const float4*)&b2[j0];
#pragma unroll
        for (int i = 0; i < 4; i++) {
            float4 hv;
            hv.x = fmaxf(acc[i][0] + bb.x, 0.f);
            hv.y = fmaxf(acc[i][1] + bb.y, 0.f);
            hv.z = fmaxf(acc[i][2] + bb.z, 0.f);
            hv.w = fmaxf(acc[i][3] + bb.w, 0.f);
            *(float4*)&As[(n0 + i) * LDP + j0] = hv;
        }
    }
    __syncthreads();

    // layer 3: a[n] = h2[n] . W3 + b3
    {
        int n = t & 63, q = t >> 6;
        float p = 0.f;
#pragma unroll
        for (int k = 0; k < 16; k++) p += As[n * LDP + q * 16 + k] * W3s[q * 16 + k];
        ps[t] = p;
    }
    __syncthreads();
    if (t < 64) {
        a_s[t] = b3[0] + ps[t] + ps[64 + t] + ps[128 + t] + ps[192 + t];
    }
    __syncthreads();

    // scatter: num[g][col_off + j] += x[n][j] * a[n], run-length compressed (batch sorted)
    {
        int j = t & 63, c = t >> 6;     // c: chunk of 16 nodes
        int i0 = c * 16;
        int lim = min(16, nvalid - i0);
        if (lim > 0) {
            float accv = 0.f;
            int gcur = bs[i0];
            for (int i = 0; i < lim; i++) {
                int n = i0 + i;
                int g = bs[n];
                if (g != gcur) {
                    atomicAdd(&num[(size_t)gcur * 128 + col_off + j], accv);
                    accv = 0.f;
                    gcur = g;
                }
                accv += x[(size_t)(base + n) * 64 + j] * a_s[n];
            }
            atomicAdd(&num[(size_t)gcur * 128 + col_off + j], accv);
        }
    }
}

// u = num / max(cnt,1); out = MLP(u) with (128->64->64->64), relu on first two
__global__ __launch_bounds__(256)
void final_mlp_kernel(const float* __restrict__ num,
                      const int* __restrict__ batch1, int N1,
                      const int* __restrict__ batch2, int N2,
                      const float* __restrict__ W1, const float* __restrict__ b1,  // [128][64]
                      const float* __restrict__ W2, const float* __restrict__ b2,  // [64][64]
                      const float* __restrict__ W3, const float* __restrict__ b3,  // [64][64]
                      float* __restrict__ out) {
    __shared__ float Us[64 * LDU];     // u tile (64 x 128), later h2
    __shared__ float W1s[128 * LDP];
    __shared__ float W2s[64 * LDP];
    __shared__ float W3s[64 * LDP];
    __shared__ float Hs[64 * LDP];     // h1
    __shared__ float inv1[64], inv2[64];

    const int t = threadIdx.x;
    const int rowbase = blockIdx.x * 64;

    // per-graph inverse counts via binary search over sorted batch arrays
    if (t < 64) {
        int g = rowbase + t;
        int c = lower_bound_i(batch1, N1, g + 1) - lower_bound_i(batch1, N1, g);
        inv1[t] = 1.0f / (float)max(c, 1);
    } else if (t < 128) {
        int g = rowbase + (t - 64);
        int c = lower_bound_i(batch2, N2, g + 1) - lower_bound_i(batch2, N2, g);
        inv2[t - 64] = 1.0f / (float)max(c, 1);
    }

    // stage weights
    {
        const float4* W1v = (const float4*)W1;
#pragma unroll
        for (int r = 0; r < 8; r++) {
            int e4 = t + 256 * r;      // 0..2047
            int e = e4 * 4;
            int k = e / 64, j = e % 64;
            *(float4*)&W1s[k * LDP + j] = W1v[e4];
        }
        const float4* W2v = (const float4*)W2;
        const float4* W3v = (const float4*)W3;
#pragma unroll
        for (int r = 0; r < 4; r++) {
            int e4 = t + 256 * r;
            int e = e4 * 4;
            int k = e / 64, j = e % 64;
            *(float4*)&W2s[k * LDP + j] = W2v[e4];
            *(float4*)&W3s[k * LDP + j] = W3v[e4];
        }
    }
    __syncthreads();

    // load u tile: u[row][col] = num[rowbase+row][col] * inv_cnt
    {
        const float4* nv = (const float4*)(num + (size_t)rowbase * 128);
#pragma unroll
        for (int r = 0; r < 8; r++) {
            int e4 = t + 256 * r;      // 0..2047
            int e = e4 * 4;
            int row = e / 128, col = e % 128;
            float4 v = nv[e4];
            float s = (col < 64) ? inv1[row] : inv2[row];
            v.x *= s; v.y *= s; v.z *= s; v.w *= s;
            *(float4*)&Us[row * LDU + col] = v;
        }
    }
    __syncthreads();

    const int fg = t & 15, ng = t >> 4;
    const int j0 = fg * 4, n0 = ng * 4;

    float acc[4][4];
#pragma unroll
    for (int i = 0; i < 4; i++) { acc[i][0] = 0.f; acc[i][1] = 0.f; acc[i][2] = 0.f; acc[i][3] = 0.f; }
    tile_gemm<128, LDU, LDP>(Us, W1s, acc, n0, j0);
    {
        float4 bb = *(const float4*)&b1[j0];
#pragma unroll
        for (int i = 0; i < 4; i++) {
            float4 hv;
            hv.x = fmaxf(acc[i][0] + bb.x, 0.f);
            hv.y = fmaxf(acc[i][1] + bb.y, 0.f);
            hv.z = fmaxf(acc[i][2] + bb.z, 0.f);
            hv.w = fmaxf(acc[i][3] + bb.w, 0.f);
            *(float4*)&Hs[(n0 + i) * LDP + j0] = hv;
        }
    }
    __syncthreads();

#pragma unroll
    for (int i = 0; i < 4; i++) { acc[i][0] = 0.f; acc[i][1] = 0.f; acc[i][2] = 0.f; acc[i][3] = 0.f; }
    tile_gemm<64, LDP, LDP>(Hs, W2s, acc, n0, j0);
    {
        float4 bb = *(const float4*)&b2[j0];
#pragma unroll
        for (int i = 0; i < 4; i++) {
            float4 hv;
            hv.x = fmaxf(acc[i][0] + bb.x, 0.f);
            hv.y = fmaxf(acc[i][1] + bb.y, 0.f);
            hv.z = fmaxf(acc[i][2] + bb.z, 0.f);
            hv.w = fmaxf(acc[i][3] + bb.w, 0.f);
            *(float4*)&Us[(n0 + i) * LDU + j0] = hv;
        }
    }
    __syncthreads();

#pragma unroll
    for (int i = 0; i < 4; i++) { acc[i][0] = 0.f; acc[i][1] = 0.f; acc[i][2] = 0.f; acc[i][3] = 0.f; }
    tile_gemm<64, LDU, LDP>(Us, W3s, acc, n0, j0);
    {
        float4 bb = *(const float4*)&b3[j0];
#pragma unroll
        for (int i = 0; i < 4; i++) {
            float4 ov;
            ov.x = acc[i][0] + bb.x;
            ov.y = acc[i][1] + bb.y;
            ov.z = acc[i][2] + bb.z;
            ov.w = acc[i][3] + bb.w;
            *(float4*)&out[(size_t)(rowbase + n0 + i) * 64 + j0] = ov;
        }
    }
}

extern "C" void kernel_launch(void* const* d_in, const int* in_sizes, int n_in,
                              void* d_out, int out_size, void* d_ws, size_t ws_size,
                              hipStream_t stream) {
    const float* x1     = (const float*)d_in[0];
    const int*   batch1 = (const int*)d_in[1];
    const float* x2     = (const float*)d_in[2];
    const int*   batch2 = (const int*)d_in[3];
    const float* aW1    = (const float*)d_in[4];
    const float* ab1    = (const float*)d_in[5];
    const float* aW2    = (const float*)d_in[6];
    const float* ab2    = (const float*)d_in[7];
    const float* aW3    = (const float*)d_in[8];
    const float* ab3    = (const float*)d_in[9];
    const float* fW1    = (const float*)d_in[10];
    const float* fb1    = (const float*)d_in[11];
    const float* fW2    = (const float*)d_in[12];
    const float* fb2    = (const float*)d_in[13];
    const float* fW3    = (const float*)d_in[14];
    const float* fb3    = (const float*)d_in[15];

    const int N1 = in_sizes[0] / 64;
    const int N2 = in_sizes[2] / 64;

    float* num = (float*)d_ws;                 // [4096][128]: cols 0..63 <- x1, 64..127 <- x2
    hipMemsetAsync(num, 0, (size_t)NGRAPHS * 128 * sizeof(float), stream);

    dim3 blk(256);
    attn_scatter_kernel<<<dim3((N1 + TILE_N - 1) / TILE_N), blk, 0, stream>>>(
        x1, batch1, N1, aW1, ab1, aW2, ab2, aW3, ab3, num, 0);
    attn_scatter_kernel<<<dim3((N2 + TILE_N - 1) / TILE_N), blk, 0, stream>>>(
        x2, batch2, N2, aW1, ab1, aW2, ab2, aW3, ab3, num, 64);
    final_mlp_kernel<<<dim3(NGRAPHS / 64), blk, 0, stream>>>(
        num, batch1, N1, batch2, N2, fW1, fb1, fW2, fb2, fW3, fb3, (float*)d_out);
}

// Round 2
// 340.485 us; speedup vs baseline: 2.1432x; 2.1432x over previous
//
#include <hip/hip_runtime.h>

// ObjectMeanDirectAttention
// Round 2: node-MLP (layers 1-2) on bf16 MFMA 16x16x32, f32 everywhere precision matters.
// - 512 threads/block, 128-node tile, wave w owns rows 16w..16w+15 (wave-local L1->L2->L3->scatter).
// - Weights staged transposed bf16 in LDS (stride 72 elems = 144B rows, 16B aligned) -> B-frag = ds_read_b128.
// - Scatter multiplies f32 x (global, L1-hot) by f32 attention scalar; run-length compressed atomics.

#define NGRAPHS 4096
#define TILE_N 128
constexpr int LDW = 72;    // bf16 LDS stride: 144 B rows (16B-aligned, 36 banks -> <=2-way aliasing)
constexpr int LDP = 68;    // f32 LDS stride for final-MLP tiles
constexpr int LDU = 132;   // f32 LDS stride for 128-wide u tile

typedef short bf16x8 __attribute__((ext_vector_type(8)));
typedef float f32x4 __attribute__((ext_vector_type(4)));

__device__ __forceinline__ unsigned short f2bf(float f) {
    unsigned u = __float_as_uint(f);
    return (unsigned short)((u + 0x7FFFu + ((u >> 16) & 1u)) >> 16);  // RNE
}

__device__ __forceinline__ int lower_bound_i(const int* __restrict__ arr, int n, int v) {
    int lo = 0, hi = n;
    while (lo < hi) {
        int mid = (lo + hi) >> 1;
        if (arr[mid] < v) lo = mid + 1; else hi = mid;
    }
    return lo;
}

// ---------------- attention MLP + weighted scatter (MFMA) ----------------
__global__ __launch_bounds__(512, 4)
void attn_scatter_mfma(const float* __restrict__ x, const int* __restrict__ batch, int N,
                       const float* __restrict__ W1, const float* __restrict__ b1,
                       const float* __restrict__ W2, const float* __restrict__ b2,
                       const float* __restrict__ W3, const float* __restrict__ b3,
                       float* __restrict__ num, int col_off) {
    __shared__ alignas(16) unsigned short W1t[64 * LDW];   // W1t[j][k] = W1[k][j]
    __shared__ alignas(16) unsigned short W2t[64 * LDW];
    __shared__ alignas(16) unsigned short Xb[TILE_N * LDW];
    __shared__ alignas(16) unsigned short H1b[TILE_N * LDW];
    __shared__ float a_s[TILE_N];

    const int t = threadIdx.x;
    const int base = blockIdx.x * TILE_N;
    const int nvalid = min(TILE_N, N - base);
    const int w  = t >> 6;    // wave 0..7 -> owns rows 16w..16w+15
    const int l  = t & 63;    // lane
    const int jj = l & 15;    // A row-in-tile / B col-in-tile
    const int kb = l >> 4;    // k-block 0..3

    // stage transposed weights (f32 global coalesced -> bf16 LDS)
#pragma unroll
    for (int r = 0; r < 8; r++) {
        int e = t + 512 * r;            // 0..4095
        int k = e >> 6, j = e & 63;
        W1t[j * LDW + k] = f2bf(W1[e]);
        W2t[j * LDW + k] = f2bf(W2[e]);
    }
    // stage x tile bf16 (zero-pad tail)
#pragma unroll
    for (int r = 0; r < 4; r++) {
        int e4 = t + 512 * r;           // 0..2047 float4s
        int node = e4 >> 4, col = (e4 & 15) * 4;
        float4 v = make_float4(0.f, 0.f, 0.f, 0.f);
        if (node < nvalid) v = *(const float4*)&x[(size_t)(base + node) * 64 + col];
        ushort4 h;
        h.x = f2bf(v.x); h.y = f2bf(v.y); h.z = f2bf(v.z); h.w = f2bf(v.w);
        *(ushort4*)&Xb[node * LDW + col] = h;
    }
    // per-lane bias / W3 slices (f32, cached)
    float b1c[4], b2c[4], w3c[4];
#pragma unroll
    for (int ct = 0; ct < 4; ct++) {
        b1c[ct] = b1[ct * 16 + jj];
        b2c[ct] = b2[ct * 16 + jj];
        w3c[ct] = W3[ct * 16 + jj];
    }
    const float b3v = b3[0];
    __syncthreads();

    // ---- layer 1: H1 = relu(X @ W1 + b1) for rows 16w..16w+15
    const int rowA = w * 16 + jj;
    bf16x8 ax0 = *(const bf16x8*)&Xb[rowA * LDW + kb * 8];        // A: row=jj, k=kb*8+i
    bf16x8 ax1 = *(const bf16x8*)&Xb[rowA * LDW + 32 + kb * 8];
    f32x4 acc1[4];
#pragma unroll
    for (int ct = 0; ct < 4; ct++) {
        bf16x8 bw0 = *(const bf16x8*)&W1t[(ct * 16 + jj) * LDW + kb * 8];       // B: col=jj, k=kb*8+i
        bf16x8 bw1 = *(const bf16x8*)&W1t[(ct * 16 + jj) * LDW + 32 + kb * 8];
        f32x4 acc = {0.f, 0.f, 0.f, 0.f};
        acc = __builtin_amdgcn_mfma_f32_16x16x32_bf16(ax0, bw0, acc, 0, 0, 0);
        acc = __builtin_amdgcn_mfma_f32_16x16x32_bf16(ax1, bw1, acc, 0, 0, 0);
        acc1[ct] = acc;
    }
    // C/D layout: col = jj, row = kb*4 + reg  [m89-verified]
#pragma unroll
    for (int ct = 0; ct < 4; ct++) {
#pragma unroll
        for (int reg = 0; reg < 4; reg++) {
            float h = fmaxf(acc1[ct][reg] + b1c[ct], 0.f);
            H1b[(w * 16 + kb * 4 + reg) * LDW + ct * 16 + jj] = f2bf(h);
        }
    }
    __syncthreads();

    // ---- layer 2 + layer 3 fused: a = relu(H1 @ W2 + b2) . W3 + b3
    bf16x8 ah0 = *(const bf16x8*)&H1b[rowA * LDW + kb * 8];
    bf16x8 ah1 = *(const bf16x8*)&H1b[rowA * LDW + 32 + kb * 8];
    float p[4] = {0.f, 0.f, 0.f, 0.f};
#pragma unroll
    for (int ct = 0; ct < 4; ct++) {
        bf16x8 bw0 = *(const bf16x8*)&W2t[(ct * 16 + jj) * LDW + kb * 8];
        bf16x8 bw1 = *(const bf16x8*)&W2t[(ct * 16 + jj) * LDW + 32 + kb * 8];
        f32x4 acc = {0.f, 0.f, 0.f, 0.f};
        acc = __builtin_amdgcn_mfma_f32_16x16x32_bf16(ah0, bw0, acc, 0, 0, 0);
        acc = __builtin_amdgcn_mfma_f32_16x16x32_bf16(ah1, bw1, acc, 0, 0, 0);
#pragma unroll
        for (int reg = 0; reg < 4; reg++) {
            float h2 = fmaxf(acc[reg] + b2c[ct], 0.f);
            p[reg] += h2 * w3c[ct];
        }
    }
    // reduce over jj (16 lanes share an output row set); masks <16 stay within the group
#pragma unroll
    for (int reg = 0; reg < 4; reg++) {
        float v = p[reg];
        v += __shfl_xor(v, 1);
        v += __shfl_xor(v, 2);
        v += __shfl_xor(v, 4);
        v += __shfl_xor(v, 8);
        if (jj == 0) a_s[w * 16 + kb * 4 + reg] = v + b3v;
    }
    __syncthreads();

    // ---- scatter: num[g][col_off+j] += x[n][j] * a[n]  (f32 x, run-length compressed)
    {
        const int j = l;            // feature 0..63
        const int i0 = w * 16;      // wave-local chunk (a_s rows written by this wave)
        int lim = min(16, nvalid - i0);
        if (lim > 0) {
            float accv = 0.f;
            int gcur = batch[base + i0];
            for (int i = 0; i < lim; i++) {
                int n = i0 + i;
                int g = batch[base + n];
                if (g != gcur) {
                    atomicAdd(&num[(size_t)gcur * 128 + col_off + j], accv);
                    accv = 0.f;
                    gcur = g;
                }
                accv += x[(size_t)(base + n) * 64 + j] * a_s[n];
            }
            atomicAdd(&num[(size_t)gcur * 128 + col_off + j], accv);
        }
    }
}

// ---------------- final MLP (f32, unchanged from round 0: negligible time) ----------------
template<int K, int LDAa, int LDBb>
__device__ __forceinline__ void tile_gemm(const float* __restrict__ As,
                                          const float* __restrict__ Bs,
                                          float acc[4][4], int n0, int j0) {
#pragma unroll 4
    for (int k0 = 0; k0 < K; k0 += 4) {
        float4 a[4], wv[4];
#pragma unroll
        for (int i = 0; i < 4; i++) a[i] = *(const float4*)&As[(n0 + i) * LDAa + k0];
#pragma unroll
        for (int kk = 0; kk < 4; kk++) wv[kk] = *(const float4*)&Bs[(k0 + kk) * LDBb + j0];
#pragma unroll
        for (int i = 0; i < 4; i++) {
            const float av0 = a[i].x, av1 = a[i].y, av2 = a[i].z, av3 = a[i].w;
            acc[i][0] += av0 * wv[0].x; acc[i][1] += av0 * wv[0].y; acc[i][2] += av0 * wv[0].z; acc[i][3] += av0 * wv[0].w;
            acc[i][0] += av1 * wv[1].x; acc[i][1] += av1 * wv[1].y; acc[i][2] += av1 * wv[1].z; acc[i][3] += av1 * wv[1].w;
            acc[i][0] += av2 * wv[2].x; acc[i][1] += av2 * wv[2].y; acc[i][2] += av2 * wv[2].z; acc[i][3] += av2 * wv[2].w;
            acc[i][0] += av3 * wv[3].x; acc[i][1] += av3 * wv[3].y; acc[i][2] += av3 * wv[3].z; acc[i][3] += av3 * wv[3].w;
        }
    }
}

__global__ __launch_bounds__(256)
void final_mlp_kernel(const float* __restrict__ num,
                      const int* __restrict__ batch1, int N1,
                      const int* __restrict__ batch2, int N2,
                      const float* __restrict__ W1, const float* __restrict__ b1,  // [128][64]
                      const float* __restrict__ W2, const float* __restrict__ b2,  // [64][64]
                      const float* __restrict__ W3, const float* __restrict__ b3,  // [64][64]
                      float* __restrict__ out) {
    __shared__ float Us[64 * LDU];
    __shared__ float W1s[128 * LDP];
    __shared__ float W2s[64 * LDP];
    __shared__ float W3s[64 * LDP];
    __shared__ float Hs[64 * LDP];
    __shared__ float inv1[64], inv2[64];

    const int t = threadIdx.x;
    const int rowbase = blockIdx.x * 64;

    if (t < 64) {
        int g = rowbase + t;
        int c = lower_bound_i(batch1, N1, g + 1) - lower_bound_i(batch1, N1, g);
        inv1[t] = 1.0f / (float)max(c, 1);
    } else if (t < 128) {
        int g = rowbase + (t - 64);
        int c = lower_bound_i(batch2, N2, g + 1) - lower_bound_i(batch2, N2, g);
        inv2[t - 64] = 1.0f / (float)max(c, 1);
    }

    {
        const float4* W1v = (const float4*)W1;
#pragma unroll
        for (int r = 0; r < 8; r++) {
            int e4 = t + 256 * r;
            int e = e4 * 4;
            int k = e / 64, j = e % 64;
            *(float4*)&W1s[k * LDP + j] = W1v[e4];
        }
        const float4* W2v = (const float4*)W2;
        const float4* W3v = (const float4*)W3;
#pragma unroll
        for (int r = 0; r < 4; r++) {
            int e4 = t + 256 * r;
            int e = e4 * 4;
            int k = e / 64, j = e % 64;
            *(float4*)&W2s[k * LDP + j] = W2v[e4];
            *(float4*)&W3s[k * LDP + j] = W3v[e4];
        }
    }
    __syncthreads();

    {
        const float4* nv = (const float4*)(num + (size_t)rowbase * 128);
#pragma unroll
        for (int r = 0; r < 8; r++) {
            int e4 = t + 256 * r;
            int e = e4 * 4;
            int row = e / 128, col = e % 128;
            float4 v = nv[e4];
            float s = (col < 64) ? inv1[row] : inv2[row];
            v.x *= s; v.y *= s; v.z *= s; v.w *= s;
            *(float4*)&Us[row * LDU + col] = v;
        }
    }
    __syncthreads();

    const int fg = t & 15, ng = t >> 4;
    const int j0 = fg * 4, n0 = ng * 4;

    float acc[4][4];
#pragma unroll
    for (int i = 0; i < 4; i++) { acc[i][0] = 0.f; acc[i][1] = 0.f; acc[i][2] = 0.f; acc[i][3] = 0.f; }
    tile_gemm<128, LDU, LDP>(Us, W1s, acc, n0, j0);
    {
        float4 bb = *(const float4*)&b1[j0];
#pragma unroll
        for (int i = 0; i < 4; i++) {
            float4 hv;
            hv.x = fmaxf(acc[i][0] + bb.x, 0.f);
            hv.y = fmaxf(acc[i][1] + bb.y, 0.f);
            hv.z = fmaxf(acc[i][2] + bb.z, 0.f);
            hv.w = fmaxf(acc[i][3] + bb.w, 0.f);
            *(float4*)&Hs[(n0 + i) * LDP + j0] = hv;
        }
    }
    __syncthreads();

#pragma unroll
    for (int i = 0; i < 4; i++) { acc[i][0] = 0.f; acc[i][1] = 0.f; acc[i][2] = 0.f; acc[i][3] = 0.f; }
    tile_gemm<64, LDP, LDP>(Hs, W2s, acc, n0, j0);
    {
        float4 bb = *(const float4*)&b2[j0];
#pragma unroll
        for (int i = 0; i < 4; i++) {
            float4 hv;
            hv.x = fmaxf(acc[i][0] + bb.x, 0.f);
            hv.y = fmaxf(acc[i][1] + bb.y, 0.f);
            hv.z = fmaxf(acc[i][2] + bb.z, 0.f);
            hv.w = fmaxf(acc[i][3] + bb.w, 0.f);
            *(float4*)&Us[(n0 + i) * LDU + j0] = hv;
        }
    }
    __syncthreads();

#pragma unroll
    for (int i = 0; i < 4; i++) { acc[i][0] = 0.f; acc[i][1] = 0.f; acc[i][2] = 0.f; acc[i][3] = 0.f; }
    tile_gemm<64, LDU, LDP>(Us, W3s, acc, n0, j0);
    {
        float4 bb = *(const float4*)&b3[j0];
#pragma unroll
        for (int i = 0; i < 4; i++) {
            float4 ov;
            ov.x = acc[i][0] + bb.x;
            ov.y = acc[i][1] + bb.y;
            ov.z = acc[i][2] + bb.z;
            ov.w = acc[i][3] + bb.w;
            *(float4*)&out[(size_t)(rowbase + n0 + i) * 64 + j0] = ov;
        }
    }
}

extern "C" void kernel_launch(void* const* d_in, const int* in_sizes, int n_in,
                              void* d_out, int out_size, void* d_ws, size_t ws_size,
                              hipStream_t stream) {
    const float* x1     = (const float*)d_in[0];
    const int*   batch1 = (const int*)d_in[1];
    const float* x2     = (const float*)d_in[2];
    const int*   batch2 = (const int*)d_in[3];
    const float* aW1    = (const float*)d_in[4];
    const float* ab1    = (const float*)d_in[5];
    const float* aW2    = (const float*)d_in[6];
    const float* ab2    = (const float*)d_in[7];
    const float* aW3    = (const float*)d_in[8];
    const float* ab3    = (const float*)d_in[9];
    const float* fW1    = (const float*)d_in[10];
    const float* fb1    = (const float*)d_in[11];
    const float* fW2    = (const float*)d_in[12];
    const float* fb2    = (const float*)d_in[13];
    const float* fW3    = (const float*)d_in[14];
    const float* fb3    = (const float*)d_in[15];

    const int N1 = in_sizes[0] / 64;
    const int N2 = in_sizes[2] / 64;

    float* num = (float*)d_ws;   // [4096][128]: cols 0..63 <- x1, 64..127 <- x2
    hipMemsetAsync(num, 0, (size_t)NGRAPHS * 128 * sizeof(float), stream);

    attn_scatter_mfma<<<dim3((N1 + TILE_N - 1) / TILE_N), dim3(512), 0, stream>>>(
        x1, batch1, N1, aW1, ab1, aW2, ab2, aW3, ab3, num, 0);
    attn_scatter_mfma<<<dim3((N2 + TILE_N - 1) / TILE_N), dim3(512), 0, stream>>>(
        x2, batch2, N2, aW1, ab1, aW2, ab2, aW3, ab3, num, 64);
    final_mlp_kernel<<<dim3(NGRAPHS / 64), dim3(256), 0, stream>>>(
        num, batch1, N1, batch2, N2, fW1, fb1, fW2, fb2, fW3, fb3, (float*)d_out);
}